// Round 9
// baseline (77.771 us; speedup 1.0000x reference)
//
#include <hip/hip_runtime.h>

typedef unsigned long long u64;

#define CC 32
#define NN 512
#define TT 12
#define BB 8
#define CHPB 4
#define NBLK 64      // 8 batches x 8 channel-groups (4 ch each); 1 CU per block
#define NTHR 512

__device__ __forceinline__ float eluf(float x){ return x>0.f ? x : (__expf(x)-1.f); }
__device__ __forceinline__ float elu3f(float x){ return eluf(eluf(eluf(x))); }
__device__ __forceinline__ float sigmf(float x){
  if (x>=0.f) return 1.f/(1.f+__expf(-x));
  float e=__expf(x); return e/(1.f+e);
}
__device__ __forceinline__ float tanhff(float x){
  return 1.f - 2.f/(__expf(2.f*x)+1.f);   // exact at saturation
}
__device__ __forceinline__ u64 pack_slot(unsigned tag, float v){
  return ((u64)tag<<32) | (u64)__float_as_uint(v);
}
__device__ __forceinline__ u64 ld_slot(u64* p){
  return __hip_atomic_load(p, __ATOMIC_RELAXED, __HIP_MEMORY_SCOPE_AGENT);
}
__device__ __forceinline__ void xch_slot(u64* p, u64 v){
  (void)__hip_atomic_exchange(p, v, __ATOMIC_RELAXED, __HIP_MEMORY_SCOPE_AGENT);
}
__device__ __forceinline__ float poll_slot(u64* p, unsigned want){
  u64 v = ld_slot(p);
  int guard = 0;
  while ((unsigned)(v>>32) != want){
    __builtin_amdgcn_s_sleep(1);
    v = ld_slot(p);
    if (++guard > 1000000) break;   // terminates instead of hanging
  }
  return __uint_as_float((unsigned)v);
}
__device__ __forceinline__ float fcomp(float4 v, int c){
  return c==0 ? v.x : c==1 ? v.y : c==2 ? v.z : v.w;   // c constant after unroll
}

__global__ __launch_bounds__(NTHR, 2)
void glstm_fused(const float* __restrict__ xg,     // (B,C,N,T)
                 const float* __restrict__ cellg,  // (B,C,N)
                 const float* __restrict__ w1g,    // (T,8,C,C)
                 const float* __restrict__ w2g,    // (T,8,C,C)
                 const float* __restrict__ biasg,  // (4,C,N,T)
                 float* __restrict__ outg,         // (B,C,N,T) ++ (B,C,N)
                 u64* slots)
{
  // 84KB pad: forces 1 block/CU (64 blocks -> 64 CUs, deterministic spin pipeline)
  __shared__ float pad[21504];
  __shared__ float outL[8][CHPB];    // head outputs: [m][local ch]
  __shared__ float redL[8];          // csum wave-partials
  __shared__ float xpartL[TT][8];
  __shared__ float cpartL[8];

  const int blk  = blockIdx.x;
  const int b    = blk >> 3;         // consecutive blocks = same batch (proven style)
  const int ch0  = (blk & 7) * CHPB;
  const int tid  = threadIdx.x;
  const int lane = tid & 63;
  const int wv   = tid >> 6;         // 0..7
  const int i0   = lane & 31;
  const int chl  = tid >> 7;         // local channel 0..3 (2 waves each)
  const int ch   = ch0 + chl;
  const int nbase= (tid & 127) * 4;  // 4 consecutive n per thread
  const int rowc = b*CC + ch;

  u64* cs_slot = slots;              // [2][256] tagged csum, parity-buffered
  u64* xs_slot = slots + 2*256;      // [12][256] tagged xsum, tag=1

  if (tid == 0) ((volatile float*)pad)[0] = 0.f;

  // ---- cell: 4 consecutive n ----
  float4 cv = *(const float4*)(cellg + rowc*NN + nbase);
  float c0=cv.x, c1=cv.y, c2=cv.z, c3=cv.w;

  // ---- x rowsums (192B contiguous per thread) + csum0; publish FIRST ----
  float xs[TT];
  #pragma unroll
  for (int t=0;t<TT;t++) xs[t]=0.f;
  const float4* xp = (const float4*)(xg + (rowc*NN + nbase)*TT);
  #pragma unroll
  for (int nl=0; nl<4; nl++){
    float4 a=xp[nl*3+0], d=xp[nl*3+1], e=xp[nl*3+2];
    xs[0]+=a.x; xs[1]+=a.y; xs[2]+=a.z;  xs[3]+=a.w;
    xs[4]+=d.x; xs[5]+=d.y; xs[6]+=d.z;  xs[7]+=d.w;
    xs[8]+=e.x; xs[9]+=e.y; xs[10]+=e.z; xs[11]+=e.w;
  }
  float cp = c0+c1+c2+c3;
  #pragma unroll
  for (int off=32; off>=1; off>>=1){
    #pragma unroll
    for (int t=0;t<TT;t++) xs[t] += __shfl_xor(xs[t], off, 64);
    cp += __shfl_xor(cp, off, 64);
  }
  if (lane == 0){
    #pragma unroll
    for (int t=0;t<TT;t++) xpartL[t][wv] = xs[t];
    cpartL[wv] = cp;
  }
  __syncthreads();
  if (tid < 48){
    int t = tid>>2, cl = tid&3;                    // waves 2cl,2cl+1 cover chl=cl
    float v = xpartL[t][2*cl] + xpartL[t][2*cl+1];
    xch_slot(&xs_slot[t*256 + b*CC + ch0 + cl], pack_slot(1u, v));
  } else if (tid < 52){
    int cl = tid - 48;
    float v = cpartL[2*cl] + cpartL[2*cl+1];
    xch_slot(&cs_slot[b*CC + ch0 + cl], pack_slot(1u, v));   // parity 0, tag 1
  }

  // ---- bias chunk 0 (steps 0-3): float4 per (gate, nl) = 64 VGPR ----
  float4 bch[4][4];
  #pragma unroll
  for (int k=0;k<4;k++)
    #pragma unroll
    for (int nl=0;nl<4;nl++)
      bch[k][nl] = *(const float4*)&biasg[((k*CC+ch)*NN + nbase+nl)*TT + 0];

  // ---- head weights t=0 (double-buffered) ----
  const int mh = (wv<4) ? (wv+4) : (wv-4);   // waves 0-3: c-heads 4-7; 4-7: x-heads 0-3
  float  w1p[2][32];
  float4 w2c[2];
  {
    const float* w1m = w1g + mh*CC*CC + i0;
    #pragma unroll
    for (int j=0;j<32;j++) w1p[0][j] = w1m[j*CC];
    w2c[0] = *(const float4*)&w2g[(mh*CC + i0)*CC + ch0];
  }

  // ---- waves 4-7: gather ALL peer xsums once (x-heads never touch fabric again) ----
  float zxr[TT];
  if (wv >= 4){
    #pragma unroll
    for (int t=0;t<TT;t++)
      zxr[t] = poll_slot(&xs_slot[t*256 + b*CC + i0], 1u);
  }

  float* houtp = outg + (rowc*NN + nbase)*TT;

  // ---- 12 sequential steps, fully unrolled, 2 barriers/step ----
  #pragma unroll
  for (int s=0;s<TT;s++){
    // phase A: head -> outL[mh][0..3]
    {
      float zs;
      if (wv < 4) zs = poll_slot(&cs_slot[(s&1)*256 + b*CC + i0], (unsigned)(s+1));
      else        zs = zxr[s];
      float s1 = 0.f;
      #pragma unroll
      for (int j=0;j<32;j++) s1 = fmaf(__shfl(zs, j, 32), w1p[s&1][j], s1);
      float h1 = eluf(eluf(s1));
      float o[4];
      #pragma unroll
      for (int cl=0; cl<4; cl++){
        float pp = h1 * fcomp(w2c[s&1], cl);
        #pragma unroll
        for (int off=16; off>=1; off>>=1) pp += __shfl_xor(pp, off, 32);
        o[cl] = elu3f(512.f*pp);
      }
      if (lane == 0){
        outL[mh][0]=o[0]; outL[mh][1]=o[1]; outL[mh][2]=o[2]; outL[mh][3]=o[3];
      }
    }
    __syncthreads();   // B1: outL ready
    const float g0 = outL[0][chl] + outL[4][chl];
    const float g1 = outL[1][chl] + outL[5][chl];
    const float g2 = outL[2][chl] + outL[6][chl];
    const float g3 = outL[3][chl] + outL[7][chl];

    // phase B: c-update for 4 n-elements (H deferred past the publish)
    {
      float ig,fg,ct;
      ig = sigmf(g0 + fcomp(bch[0][0], s&3));
      fg = sigmf(g1 + fcomp(bch[1][0], s&3));
      ct = tanhff(g3 + fcomp(bch[3][0], s&3));
      c0 = fg*c0 + ig*ct;
      ig = sigmf(g0 + fcomp(bch[0][1], s&3));
      fg = sigmf(g1 + fcomp(bch[1][1], s&3));
      ct = tanhff(g3 + fcomp(bch[3][1], s&3));
      c1 = fg*c1 + ig*ct;
      ig = sigmf(g0 + fcomp(bch[0][2], s&3));
      fg = sigmf(g1 + fcomp(bch[1][2], s&3));
      ct = tanhff(g3 + fcomp(bch[3][2], s&3));
      c2 = fg*c2 + ig*ct;
      ig = sigmf(g0 + fcomp(bch[0][3], s&3));
      fg = sigmf(g1 + fcomp(bch[1][3], s&3));
      ct = tanhff(g3 + fcomp(bch[3][3], s&3));
      c3 = fg*c3 + ig*ct;
    }
    float csp = c0+c1+c2+c3;
    #pragma unroll
    for (int off=32; off>=1; off>>=1) csp += __shfl_xor(csp, off, 64);
    if (lane == 0) redL[wv] = csp;
    __syncthreads(); // B2: redL ready
    if (s < TT-1 && tid < 4){
      float tot = redL[2*tid] + redL[2*tid+1];
      xch_slot(&cs_slot[((s+1)&1)*256 + b*CC + ch0 + tid],
               pack_slot((unsigned)(s+2), tot));
    }

    // H outputs (off the critical recurrence)
    houtp[0*TT + s] = sigmf(g2 + fcomp(bch[2][0], s&3)) * tanhff(c0);
    houtp[1*TT + s] = sigmf(g2 + fcomp(bch[2][1], s&3)) * tanhff(c1);
    houtp[2*TT + s] = sigmf(g2 + fcomp(bch[2][2], s&3)) * tanhff(c2);
    houtp[3*TT + s] = sigmf(g2 + fcomp(bch[2][3], s&3)) * tanhff(c3);

    // weight prefetch for t=s+1 (after publish; hidden under next poll)
    if (s < TT-1){
      const float* w1m = w1g + ((s+1)*8 + mh)*CC*CC + i0;
      #pragma unroll
      for (int j=0;j<32;j++) w1p[(s+1)&1][j] = w1m[j*CC];
      w2c[(s+1)&1] = *(const float4*)&w2g[(((s+1)*8 + mh)*CC + i0)*CC + ch0];
    }
    // bias chunk reload every 4 steps (L2-resident: 8 blocks/XCD share the slice)
    if ((s&3)==3 && s < TT-1){
      #pragma unroll
      for (int k=0;k<4;k++)
        #pragma unroll
        for (int nl=0;nl<4;nl++)
          bch[k][nl] = *(const float4*)&biasg[((k*CC+ch)*NN + nbase+nl)*TT + (s+1)];
    }
  }

  // ---- final cell state ----
  *(float4*)(outg + BB*CC*NN*TT + rowc*NN + nbase) = make_float4(c0,c1,c2,c3);
}

extern "C" void kernel_launch(void* const* d_in, const int* in_sizes, int n_in,
                              void* d_out, int out_size, void* d_ws, size_t ws_size,
                              hipStream_t stream)
{
  (void)in_sizes; (void)n_in; (void)out_size; (void)ws_size;
  // setup_inputs order: input, cell, adj, w1, a1, w2, a2, bias
  const float* xg    = (const float*)d_in[0];
  const float* cellg = (const float*)d_in[1];
  const float* w1g   = (const float*)d_in[3];
  const float* w2g   = (const float*)d_in[5];
  const float* biasg = (const float*)d_in[7];
  float* outg = (float*)d_out;
  u64* slots = (u64*)d_ws;

  // reset sync tags every launch (ws is not re-poisoned between replays)
  hipMemsetAsync(d_ws, 0, (size_t)(2*256 + TT*256)*sizeof(u64), stream);
  glstm_fused<<<dim3(NBLK), dim3(NTHR), 0, stream>>>(xg, cellg, w1g, w2g, biasg, outg, slots);
}

// Round 10
// 57.717 us; speedup vs baseline: 1.3475x; 1.3475x over previous
//
#include <hip/hip_runtime.h>

typedef unsigned long long u64;

#define CC 32
#define NN 512
#define TT 12
#define NBLK 256     // one block per (batch, channel); == CU count
#define NTHR 256     // 2 n-elements per thread (proven shape)

__device__ __forceinline__ float eluf(float x){ return x>0.f ? x : (__expf(x)-1.f); }
__device__ __forceinline__ float elu3f(float x){ return eluf(eluf(eluf(x))); }
__device__ __forceinline__ float sigmf(float x){
  if (x>=0.f) return 1.f/(1.f+__expf(-x));
  float e=__expf(x); return e/(1.f+e);
}
__device__ __forceinline__ float tanhff(float x){
  return 1.f - 2.f/(__expf(2.f*x)+1.f);   // exact at saturation
}
__device__ __forceinline__ u64 pack_slot(unsigned tag, float v){
  return ((u64)tag<<32) | (u64)__float_as_uint(v);
}
__device__ __forceinline__ u64 ld_slot(u64* p){
  return __hip_atomic_load(p, __ATOMIC_RELAXED, __HIP_MEMORY_SCOPE_AGENT);
}
__device__ __forceinline__ void xch_slot(u64* p, u64 v){
  (void)__hip_atomic_exchange(p, v, __ATOMIC_RELAXED, __HIP_MEMORY_SCOPE_AGENT);
}
__device__ __forceinline__ float poll_slot(u64* p, unsigned want){
  u64 v = ld_slot(p);
  int guard = 0;
  while ((unsigned)(v>>32) != want){
    __builtin_amdgcn_s_sleep(1);
    v = ld_slot(p);
    if (++guard > 1000000) break;   // terminates instead of hanging
  }
  return __uint_as_float((unsigned)v);
}

__global__ __launch_bounds__(NTHR, 1)
void glstm_fused(const float* __restrict__ xg,     // (B,C,N,T)
                 const float* __restrict__ cellg,  // (B,C,N)
                 const float* __restrict__ w1g,    // (T,8,C,C)
                 const float* __restrict__ w2g,    // (T,8,C,C)
                 const float* __restrict__ biasg,  // (4,C,N,T)
                 float* __restrict__ outg,         // (B,C,N,T) ++ (B,C,N)
                 u64* slots)
{
  // 96KB bias tile -> 1 block/CU (proven residency for the spin pipeline)
  __shared__ float biasL[4][TT][NN];
  __shared__ float preS[2][4];       // parity-buffered gate pre-activations
  __shared__ float redS[2][4];       // parity-buffered csum wave-partials
  __shared__ float wpart[13][4];
  __shared__ unsigned cntS[2];       // arrival counters (parity)

  const int blk  = blockIdx.x;
  const int b    = blk >> 5;         // proven mapping (XCD-local mapping hurts)
  const int ch   = blk & 31;
  const int row  = blk;
  const int tid  = threadIdx.x;
  const int lane = tid & 63;
  const int wv   = tid >> 6;         // 0..3
  const int i0   = lane & 31;

  if (tid == 0){ cntS[0] = 0u; cntS[1] = 0u; }

  u64* cs_slot = slots;              // [2][NBLK] tagged csum, parity-buffered
  u64* xs_slot = slots + 2*NBLK;     // [TT][NBLK] tagged xsum, tag=1

  // ---- per-thread state: 2 n-elements ----
  const int n0 = 2*tid;
  float2 cc2 = *(const float2*)(cellg + row*NN + n0);
  float c0 = cc2.x, c1 = cc2.y;

  // ---- x rowsums per t + csum(state0) FIRST (publish gates the batch group) ----
  float xs[TT];
  #pragma unroll
  for (int t=0;t<TT;t++) xs[t]=0.f;
  const float* xrow = xg + row*NN*TT;
  #pragma unroll
  for (int half=0; half<2; half++){
    int n = tid + half*256;
    const float4* p = (const float4*)(xrow + n*TT);
    float4 v0=p[0], v1=p[1], v2=p[2];
    xs[0]+=v0.x;  xs[1]+=v0.y;  xs[2]+=v0.z;  xs[3]+=v0.w;
    xs[4]+=v1.x;  xs[5]+=v1.y;  xs[6]+=v1.z;  xs[7]+=v1.w;
    xs[8]+=v2.x;  xs[9]+=v2.y;  xs[10]+=v2.z; xs[11]+=v2.w;
  }
  float cp = c0 + c1;
  #pragma unroll
  for (int off=32; off>=1; off>>=1){
    #pragma unroll
    for (int t=0;t<TT;t++) xs[t] += __shfl_xor(xs[t], off, 64);
    cp += __shfl_xor(cp, off, 64);
  }
  if (lane == 0){
    #pragma unroll
    for (int t=0;t<TT;t++) wpart[t][wv] = xs[t];
    wpart[12][wv] = cp;
  }
  __syncthreads();
  if (tid < 13){
    float v = wpart[tid][0]+wpart[tid][1]+wpart[tid][2]+wpart[tid][3];
    if (tid < TT) xch_slot(&xs_slot[tid*NBLK + row], pack_slot(1u, v));
    else          xch_slot(&cs_slot[row],            pack_slot(1u, v));  // parity 0
  }

  // ---- bias -> LDS (after publish; overlaps peers' publish latency) ----
  #pragma unroll
  for (int k=0;k<4;k++){
    #pragma unroll
    for (int half=0; half<2; half++){
      int n = tid + half*256;
      const float4* p = (const float4*)(biasg + ((k*CC + ch)*NN + n)*TT);
      float4 v0=p[0], v1=p[1], v2=p[2];
      biasL[k][0][n]=v0.x;  biasL[k][1][n]=v0.y;  biasL[k][2][n]=v0.z;  biasL[k][3][n]=v0.w;
      biasL[k][4][n]=v1.x;  biasL[k][5][n]=v1.y;  biasL[k][6][n]=v1.z;  biasL[k][7][n]=v1.w;
      biasL[k][8][n]=v2.x;  biasL[k][9][n]=v2.y;  biasL[k][10][n]=v2.z; biasL[k][11][n]=v2.w;
    }
  }

  // ---- head assignment + weight double-buffer (t=0 now) ----
  const int m = wv + ((lane >> 5) << 2);   // lanes<32: x-heads 0-3; lanes>=32: c-heads 4-7
  float w1p[2][32];
  float w2p[2];
  {
    const float* w1m = w1g + m*CC*CC + i0;
    #pragma unroll
    for (int j=0;j<32;j++) w1p[0][j] = w1m[j*CC];
    w2p[0] = w2g[(m*CC + i0)*CC + ch];
  }

  // ---- gather ALL peer xsums to registers once ----
  float zxr[TT];
  #pragma unroll
  for (int t=0;t<TT;t++)
    zxr[t] = poll_slot(&xs_slot[t*NBLK + b*CC + i0], 1u);

  // ---- 12 sequential steps, fully unrolled, ONE barrier per step ----
  float hm0[TT], hm1[TT];
  #pragma unroll
  for (int s=0;s<TT;s++){
    // hop: all lanes poll this step's peer csum (clean vmcnt: drained last step)
    float csv = poll_slot(&cs_slot[(s&1)*NBLK + b*CC + i0], (unsigned)(s+1));
    float zs = (lane < 32) ? zxr[s] : csv;

    // head matvec from prefetched registers (no global loads post-poll)
    float pa = 0.f, pb = 0.f;
    #pragma unroll
    for (int j=0;j<16;j++){
      pa = fmaf(__shfl(zs, j,    32), w1p[s&1][j],    pa);
      pb = fmaf(__shfl(zs, j+16, 32), w1p[s&1][j+16], pb);
    }
    float s1 = pa + pb;
    float h1 = eluf(eluf(s1));
    float pp = h1 * w2p[s&1];
    #pragma unroll
    for (int off=16; off>=1; off>>=1) pp += __shfl_xor(pp, off, 32);
    float ov = elu3f(512.f*pp);
    float prew = ov + __shfl_xor(ov, 32, 64);      // x-head + c-head
    if (lane == 0) preS[s&1][wv] = prew;

    // bias -> regs before the barrier (gate phase = pure VALU)
    float b00 = biasL[0][s][n0], b01 = biasL[0][s][n0+1];
    float b10 = biasL[1][s][n0], b11 = biasL[1][s][n0+1];
    float b20 = biasL[2][s][n0], b21 = biasL[2][s][n0+1];
    float b30 = biasL[3][s][n0], b31 = biasL[3][s][n0+1];

    __syncthreads();   // B1: preS[s&1] ready (the ONLY barrier in the loop)
    const float g0 = preS[s&1][0], g1 = preS[s&1][1];
    const float g2 = preS[s&1][2], g3 = preS[s&1][3];

    float ig0 = sigmf(g0 + b00);
    float fg0 = sigmf(g1 + b10);
    float ct0 = tanhff(g3 + b30);
    float ig1 = sigmf(g0 + b01);
    float fg1 = sigmf(g1 + b11);
    float ct1 = tanhff(g3 + b31);
    c0 = fg0*c0 + ig0*ct0;
    c1 = fg1*c1 + ig1*ct1;

    if (s < TT-1){
      const int par = (s+1)&1;
      // barrier-free publish: per-wave partial + LDS arrival counter; the
      // 4th arriver sums in FIXED order (deterministic FP) and publishes.
      float csp = c0 + c1;
      #pragma unroll
      for (int off=32; off>=1; off>>=1) csp += __shfl_xor(csp, off, 64);
      if (lane == 0){
        redS[par][wv] = csp;                        // ds_write ...
        unsigned old = atomicAdd(&cntS[par], 1u);   // ... ordered before counter
        if (old == 3u){
          volatile float* rp = &redS[par][0];       // no hoist above the atomic
          float tot = rp[0]+rp[1]+rp[2]+rp[3];
          xch_slot(&cs_slot[par*NBLK + row], pack_slot((unsigned)(s+2), tot));
          cntS[par] = 0u;   // next reuse is s+2, causally after this publish
        }
      }
      // prefetch next step's weights AFTER the publish point ...
      const float* w1m = w1g + ((s+1)*8 + m)*CC*CC + i0;
      #pragma unroll
      for (int j=0;j<32;j++) w1p[par][j] = w1m[j*CC];
      w2p[par] = w2g[(((s+1)*8 + m)*CC + i0)*CC + ch];
      // ... and DRAIN now: the ~400-600cy flight overlaps the producers'
      // publish flight instead of sitting inside next step's poll_slot
      // (whose s_waitcnt vmcnt(0) would otherwise drain these 33 loads
      // before even inspecting the tag).
      __asm__ __volatile__("s_waitcnt vmcnt(0)" ::: "memory");
    }

    hm0[s] = sigmf(g2 + b20) * tanhff(c0);
    hm1[s] = sigmf(g2 + b21) * tanhff(c1);
  }

  // ---- coalesced epilogue: 2 n-rows x 12 t contiguous ----
  float4* op = (float4*)(outg + (row*NN + n0)*TT);
  op[0] = make_float4(hm0[0], hm0[1], hm0[2],  hm0[3]);
  op[1] = make_float4(hm0[4], hm0[5], hm0[6],  hm0[7]);
  op[2] = make_float4(hm0[8], hm0[9], hm0[10], hm0[11]);
  op[3] = make_float4(hm1[0], hm1[1], hm1[2],  hm1[3]);
  op[4] = make_float4(hm1[4], hm1[5], hm1[6],  hm1[7]);
  op[5] = make_float4(hm1[8], hm1[9], hm1[10], hm1[11]);
  *(float2*)(outg + NBLK*NN*TT + row*NN + n0) = make_float2(c0, c1);
}

extern "C" void kernel_launch(void* const* d_in, const int* in_sizes, int n_in,
                              void* d_out, int out_size, void* d_ws, size_t ws_size,
                              hipStream_t stream)
{
  (void)in_sizes; (void)n_in; (void)out_size; (void)ws_size;
  // setup_inputs order: input, cell, adj, w1, a1, w2, a2, bias
  const float* xg    = (const float*)d_in[0];
  const float* cellg = (const float*)d_in[1];
  const float* w1g   = (const float*)d_in[3];
  const float* w2g   = (const float*)d_in[5];
  const float* biasg = (const float*)d_in[7];
  float* outg = (float*)d_out;
  u64* slots = (u64*)d_ws;

  // reset sync tags every launch (ws is not re-poisoned between replays)
  hipMemsetAsync(d_ws, 0, (size_t)(2*NBLK + TT*NBLK)*sizeof(u64), stream);
  glstm_fused<<<dim3(NBLK), dim3(NTHR), 0, stream>>>(xg, cellg, w1g, w2g, biasg, outg, slots);
}